// Round 12
// baseline (165.559 us; speedup 1.0000x reference)
//
#include <hip/hip_runtime.h>

#define NVOX  160000
#define KOFF  27
#define EPSV  1e-5f
#define SLOPE 0.01f
#define CBLK  10000   // conv blocks: one 16-voxel tile per block, 4 waves split k
#define WPELE (KOFF * 2 * 64 * 8)   // 27648 packed B-frag elements

using bf16x8 = __attribute__((ext_vector_type(8))) __bf16;
using f32x4  = __attribute__((ext_vector_type(4))) float;
using f32x2  = __attribute__((ext_vector_type(2))) float;
using i32x4  = __attribute__((ext_vector_type(4))) int;
using u16    = unsigned short;
typedef __attribute__((ext_vector_type(4), aligned(4))) int i32x4u;

// Evidence log: f32 flavor (R2-R8); coop launch no-ops (R9); LDS W-pack kills
// occupancy + bank conflicts (R10); source-level gather batching is always
// collapsed by the register allocator -> per-wave serial chain ~45k cyc is the
// bottleneck (R10/R11). This round: cut chain 4x by splitting k across waves.

// ---------------------------------------------------------------------------
// Dispatch 1: pack W[27][32][32] f32 -> bf16 MFMA B-frag order (global).
// frag (k,f): couts f*16..f*16+15; lane L reg j holds B[c=(L>>4)*8+j][d=f*16+(L&15)]
// ---------------------------------------------------------------------------
__global__ void pack_weights(const float* __restrict__ w, u16* __restrict__ wp) {
    int tid = blockIdx.x * blockDim.x + threadIdx.x;   // 27648
    if (tid >= WPELE) return;
    int j = tid & 7;
    int L = (tid >> 3) & 63;
    int f = (tid >> 9) & 1;
    int k = tid >> 10;
    int c = ((L >> 4) << 3) + j;
    int d = (f << 4) + (L & 15);
    __bf16 b = (__bf16)w[(k * 32 + c) * 32 + d];
    wp[tid] = __builtin_bit_cast(u16, b);
}

// ---------------------------------------------------------------------------
// Dispatch 2: sparse conv. Block = one 16-voxel tile; wave w covers offsets
// k in [7w, 7w+7) (wave 3: 6 + sentinel). Per-offset: wave-uniform ballot
// skip; taken: clamped 2x dwordx4 f32 gather -> bf16 A-frag -> 2 MFMAs.
// Partial accs -> LDS -> block combine -> coalesced out store + stats row.
// ---------------------------------------------------------------------------
__global__ __launch_bounds__(256) void conv_mfma(
    const float* __restrict__ feat,     // [N][32]
    const int*  __restrict__ nbr,       // [N][27]
    const i32x4* __restrict__ wp,       // packed B-frags
    float* __restrict__ out,            // [N][32] (d_out)
    float* __restrict__ partials)       // [CBLK][64] row-major
{
    __shared__ float pacc[4 * 512];     // [wave][vox*32+ch]
    __shared__ float ssum[32], ssq[32];

    const int t    = threadIdx.x;
    const int w    = t >> 6;
    const int lane = t & 63;
    const int m    = lane & 15;
    const int q    = lane >> 4;
    const int tile = blockIdx.x;
    const int vbase = tile * 16;

    if (t < 32) { ssum[t] = 0.f; ssq[t] = 0.f; }

    // ---- this wave's 7 neighbor ids (2 overlapping vector loads) ----
    const int k0 = w * 7;
    const int* row = nbr + (size_t)(vbase + m) * KOFF;
    i32x4 a4 = *(const i32x4u*)(row + k0);
    i32x4 b4 = *(const i32x4u*)(row + k0 + (w == 3 ? 2 : 3));
    int id[7];
    id[0] = a4[0]; id[1] = a4[1]; id[2] = a4[2]; id[3] = a4[3];
    if (w == 3) { id[4] = b4[2]; id[5] = b4[3]; id[6] = -1; }  // k=27 sentinel
    else        { id[4] = b4[1]; id[5] = b4[2]; id[6] = b4[3]; }

    f32x4 acc0 = {}, acc1 = {};

#pragma unroll
    for (int j = 0; j < 7; ++j) {
        if (__ballot(id[j] >= 0)) {                // wave-uniform skip
            int v_id = id[j];
            int safe = v_id >= 0 ? v_id : 0;       // invalid -> hot row 0 (L1)
            const f32x4* fp = (const f32x4*)(feat + (size_t)safe * 32 + q * 8);
            f32x4 lo = fp[0], hi = fp[1];
            bf16x8 tv;
#pragma unroll
            for (int jj = 0; jj < 4; ++jj) {
                tv[jj]     = (__bf16)lo[jj];
                tv[4 + jj] = (__bf16)hi[jj];
            }
            bf16x8 z = {};
            bf16x8 a = (v_id < 0) ? z : tv;
            int k = k0 + j;
            i32x4 b0r = wp[(k * 2 + 0) * 64 + lane];
            i32x4 b1r = wp[(k * 2 + 1) * 64 + lane];
            bf16x8 b0 = __builtin_bit_cast(bf16x8, b0r);
            bf16x8 b1 = __builtin_bit_cast(bf16x8, b1r);
            acc0 = __builtin_amdgcn_mfma_f32_16x16x32_bf16(a, b0, acc0, 0, 0, 0);
            acc1 = __builtin_amdgcn_mfma_f32_16x16x32_bf16(a, b1, acc1, 0, 0, 0);
        }
    }

    // ---- partial accs -> LDS (C/D: vox = q*4+r, ch = m / 16+m) ----
#pragma unroll
    for (int r = 0; r < 4; ++r) {
        int vox = q * 4 + r;
        pacc[w * 512 + vox * 32 + m]      = acc0[r];
        pacc[w * 512 + vox * 32 + 16 + m] = acc1[r];
    }
    __syncthreads();

    // ---- combine 4 waves; coalesced store; stats ----
    int e0 = t * 2;
    float f0 = pacc[e0]     + pacc[512 + e0]     + pacc[1024 + e0]     + pacc[1536 + e0];
    float f1 = pacc[e0 + 1] + pacc[512 + e0 + 1] + pacc[1024 + e0 + 1] + pacc[1536 + e0 + 1];
    f32x2 st = {f0, f1};
    *(f32x2*)(out + (size_t)vbase * 32 + e0) = st;

    atomicAdd(&ssum[e0 & 31], f0);
    atomicAdd(&ssq [e0 & 31], f0 * f0);
    atomicAdd(&ssum[(e0 + 1) & 31], f1);
    atomicAdd(&ssq [(e0 + 1) & 31], f1 * f1);
    __syncthreads();

    if (t < 64)
        partials[(size_t)tile * 64 + t] = (t < 32) ? ssum[t] : ssq[t - 32];
}

// ---------------------------------------------------------------------------
// Dispatch 3: 64 blocks; block c sums partials[:, c] -> stats[c]
// ---------------------------------------------------------------------------
__global__ __launch_bounds__(256) void reduce_stats(
    const float* __restrict__ partials, float* __restrict__ stats)
{
    int c = blockIdx.x;
    float s = 0.f;
    for (int p = threadIdx.x; p < CBLK; p += 256) s += partials[(size_t)p * 64 + c];
#pragma unroll
    for (int off = 1; off < 64; off <<= 1) s += __shfl_xor(s, off, 64);
    __shared__ float sd[4];
    int lane = threadIdx.x & 63, w = threadIdx.x >> 6;
    if (lane == 0) sd[w] = s;
    __syncthreads();
    if (threadIdx.x == 0) stats[c] = sd[0] + sd[1] + sd[2] + sd[3];
}

// ---------------------------------------------------------------------------
// Dispatch 4: BN + LeakyReLU in place; scale/shift from stats[64].
// ---------------------------------------------------------------------------
__global__ __launch_bounds__(256) void apply_bn(
    f32x4* __restrict__ o, const float* __restrict__ stats,
    const float* __restrict__ gamma, const float* __restrict__ beta)
{
    __shared__ float s[64];
    int t = threadIdx.x;
    if (t < 32) {
        float mean = stats[t] * (1.f / NVOX);
        float var  = stats[32 + t] * (1.f / NVOX) - mean * mean;
        float rstd = rsqrtf(var + EPSV);
        float scale = gamma[t] * rstd;
        s[t]      = scale;
        s[32 + t] = beta[t] - mean * scale;
    }
    __syncthreads();
    int i = blockIdx.x * 256 + t;
#pragma unroll
    for (int rep = 0; rep < 2; ++rep) {
        int i2 = i * 2 + rep;               // 1,280,000 vec4 total
        f32x4 v = o[i2];
        int c0 = (i2 & 7) * 4;
        f32x4 r;
#pragma unroll
        for (int j = 0; j < 4; ++j) {
            float y = v[j] * s[c0 + j] + s[32 + c0 + j];
            r[j] = (y >= 0.f) ? y : SLOPE * y;
        }
        o[i2] = r;
    }
}

// ---------------------------------------------------------------------------
extern "C" void kernel_launch(void* const* d_in, const int* in_sizes, int n_in,
                              void* d_out, int out_size, void* d_ws, size_t ws_size,
                              hipStream_t stream) {
    const float* feat  = (const float*)d_in[0];  // [N][32] f32
    const int*   nbr   = (const int*)d_in[1];    // [N][27] int32
    const float* w     = (const float*)d_in[2];  // [27][32][32] f32
    // d_in[3] = bias: cancels exactly in BN — unused
    const float* gamma = (const float*)d_in[4];
    const float* beta  = (const float*)d_in[5];

    char* ws = (char*)d_ws;                       // ws ~256 MB
    u16*   wp       = (u16*)ws;                   // 55,296 B
    float* partials = (float*)(ws + 55296);       // 10000*64*4 = 2,560,000 B
    float* stats    = (float*)(ws + 55296 + 2560000);  // 256 B

    pack_weights<<<108, 256, 0, stream>>>(w, wp);
    conv_mfma<<<CBLK, 256, 0, stream>>>(feat, nbr, (const i32x4*)wp,
                                        (float*)d_out, partials);
    reduce_stats<<<64, 256, 0, stream>>>(partials, stats);
    apply_bn<<<2500, 256, 0, stream>>>((f32x4*)d_out, stats, gamma, beta);
}

// Round 13
// 165.544 us; speedup vs baseline: 1.0001x; 1.0001x over previous
//
#include <hip/hip_runtime.h>

#define NVOX  160000
#define KOFF  27
#define EPSV  1e-5f
#define SLOPE 0.01f
#define CBLK  2500    // conv blocks: 4 waves/block, each wave owns a 16-vox tile
#define WPELE (KOFF * 2 * 64 * 8)   // 27648 packed B-frag elements

using bf16x8 = __attribute__((ext_vector_type(8))) __bf16;
using f32x4  = __attribute__((ext_vector_type(4))) float;
using i32x4  = __attribute__((ext_vector_type(4))) int;
using u16    = unsigned short;
using u16x4  = __attribute__((ext_vector_type(4))) u16;

// Evidence log: f32 flavor (R2-R8); coop launch no-ops (R9); big-LDS W pack
// kills occupancy (R10); register-batched gathers collapsed by regalloc
// (R10/R11); high occupancy alone doesn't help (R12: 71% occ, still 63us,
// all pipes idle) => bound by scattered-segment processing in the vector
// memory path. This round: segment-count diet (coalesced nbr staging via
// LDS, single-load bf16 gathers, coalesced LDS-transposed stores).

// ---------------------------------------------------------------------------
// Dispatch 1: prep — pack W into bf16 B-frag order + convert feat to bf16.
// ---------------------------------------------------------------------------
__global__ __launch_bounds__(256) void prep(
    const float* __restrict__ w, const float* __restrict__ feat,
    u16* __restrict__ wp, u16* __restrict__ featb)
{
    int tid = blockIdx.x * 256 + threadIdx.x;
    // pack W: frag (k,f): lane L reg j = B[c=(L>>4)*8+j][d=f*16+(L&15)]
    if (tid < WPELE) {
        int j = tid & 7;
        int L = (tid >> 3) & 63;
        int f = (tid >> 9) & 1;
        int k = tid >> 10;
        int c = ((L >> 4) << 3) + j;
        int d = (f << 4) + (L & 15);
        __bf16 b = (__bf16)w[(k * 32 + c) * 32 + d];
        wp[tid] = __builtin_bit_cast(u16, b);
    }
    // feat f32 -> bf16: 1,280,000 vec4, 2 per thread
    const f32x4* fv = (const f32x4*)feat;
    u16x4* ov = (u16x4*)featb;
#pragma unroll
    for (int rep = 0; rep < 2; ++rep) {
        int i = tid * 2 + rep;
        f32x4 v = fv[i];
        u16x4 o;
#pragma unroll
        for (int j = 0; j < 4; ++j) {
            __bf16 b = (__bf16)v[j];
            o[j] = __builtin_bit_cast(u16, b);
        }
        ov[i] = o;
    }
}

// ---------------------------------------------------------------------------
// Dispatch 2: sparse conv via MFMA. 4 waves/block, wave = one 16-voxel tile.
// nbr: tile's 432 contiguous ints staged coalesced into LDS (7 dword loads),
//      lanes read their 27 ids from LDS registers-up-front.
// k-loop: serial 27, wave-uniform ballot skip; taken: ONE clamped dwordx4
//      bf16 gather -> A-frag -> 2 MFMAs (B-frags streamed from global wp).
// out: acc -> per-wave LDS tile -> 2 coalesced f32x4 stores (2 KB contig).
// stats: shfl + LDS block-reduce -> 64 line-padded global atomics.
// ---------------------------------------------------------------------------
__global__ __launch_bounds__(256) void conv_mfma(
    const u16*  __restrict__ featb,     // [N][32] bf16
    const int*  __restrict__ nbr,       // [N][27]
    const i32x4* __restrict__ wp,       // packed B-frags
    float* __restrict__ out,            // [N][32] (d_out)
    float* __restrict__ stats)          // [64][16] line-padded accumulators
{
    __shared__ int   snbr[4][432];      // 6912 B
    __shared__ float sout[4][512];      // 8192 B
    __shared__ float red[4][64];

    const int t    = threadIdx.x;
    const int w    = t >> 6;
    const int lane = t & 63;
    const int m    = lane & 15;
    const int q    = lane >> 4;
    const int tile = blockIdx.x * 4 + w;    // 0..9999
    const int vbase = tile * 16;

    // ---- stage this tile's nbr block coalesced (432 contiguous ints) ----
    const int* nb = nbr + (size_t)vbase * KOFF;
#pragma unroll
    for (int i = 0; i < 7; ++i) {
        int idx = lane + i * 64;
        if (idx < 432) snbr[w][idx] = nb[idx];
    }
    // lane's 27 ids from LDS (bank stride 27: conflict-light)
    int id[27];
#pragma unroll
    for (int k = 0; k < KOFF; ++k) id[k] = snbr[w][m * KOFF + k];

    f32x4 acc0 = {}, acc1 = {};

    // ---- serial 27 k-loop, ballot-gated ----
#pragma unroll
    for (int k = 0; k < KOFF; ++k) {
        if (__ballot(id[k] >= 0)) {
            int v_id = id[k];
            int safe = v_id >= 0 ? v_id : 0;     // invalid -> hot row 0
            i32x4 ar = *(const i32x4*)(featb + (size_t)safe * 32 + q * 8);
            i32x4 z4 = {0, 0, 0, 0};
            i32x4 av = (v_id < 0) ? z4 : ar;
            bf16x8 a = __builtin_bit_cast(bf16x8, av);
            i32x4 b0r = wp[(k * 2 + 0) * 64 + lane];
            i32x4 b1r = wp[(k * 2 + 1) * 64 + lane];
            bf16x8 b0 = __builtin_bit_cast(bf16x8, b0r);
            bf16x8 b1 = __builtin_bit_cast(bf16x8, b1r);
            acc0 = __builtin_amdgcn_mfma_f32_16x16x32_bf16(a, b0, acc0, 0, 0, 0);
            acc1 = __builtin_amdgcn_mfma_f32_16x16x32_bf16(a, b1, acc1, 0, 0, 0);
        }
    }

    // ---- stats: reduce over q (shfl), then block LDS reduce ----
    float s0 = 0, s1 = 0, sq0 = 0, sq1 = 0;
#pragma unroll
    for (int r = 0; r < 4; ++r) {
        float x0 = acc0[r], x1 = acc1[r];
        s0 += x0; sq0 += x0 * x0;
        s1 += x1; sq1 += x1 * x1;
    }
    s0  += __shfl_xor(s0, 16, 64);  s0  += __shfl_xor(s0, 32, 64);
    s1  += __shfl_xor(s1, 16, 64);  s1  += __shfl_xor(s1, 32, 64);
    sq0 += __shfl_xor(sq0, 16, 64); sq0 += __shfl_xor(sq0, 32, 64);
    sq1 += __shfl_xor(sq1, 16, 64); sq1 += __shfl_xor(sq1, 32, 64);
    if (lane < 16) {
        red[w][m]      = s0;
        red[w][16 + m] = s1;
        red[w][32 + m] = sq0;
        red[w][48 + m] = sq1;
    }

    // ---- output: acc -> per-wave LDS -> coalesced stores ----
    // C/D: vox = q*4+r, ch = m (+16)
#pragma unroll
    for (int r = 0; r < 4; ++r) {
        int vox = q * 4 + r;
        sout[w][vox * 32 + m]      = acc0[r];
        sout[w][vox * 32 + 16 + m] = acc1[r];
    }
    // wave-local LDS round-trip: compiler inserts lgkmcnt wait; no barrier
    // needed (each wave reads only its own region)
#pragma unroll
    for (int h = 0; h < 2; ++h) {
        f32x4 v = *(const f32x4*)&sout[w][h * 256 + lane * 4];
        *(f32x4*)(out + (size_t)vbase * 32 + h * 256 + lane * 4) = v;
    }

    __syncthreads();
    if (t < 64) {
        float v = red[0][t] + red[1][t] + red[2][t] + red[3][t];
        atomicAdd(&stats[t * 16], v);   // 64B lines; ws poison -3e-13 ok
    }
}

// ---------------------------------------------------------------------------
// Dispatch 3: BN + LeakyReLU in place; scale/shift from line-padded stats.
// ---------------------------------------------------------------------------
__global__ __launch_bounds__(256) void apply_bn(
    f32x4* __restrict__ o, const float* __restrict__ stats,
    const float* __restrict__ gamma, const float* __restrict__ beta)
{
    __shared__ float s[64];
    int t = threadIdx.x;
    if (t < 32) {
        float mean = stats[t * 16] * (1.f / NVOX);
        float var  = stats[(32 + t) * 16] * (1.f / NVOX) - mean * mean;
        float rstd = rsqrtf(var + EPSV);
        float scale = gamma[t] * rstd;
        s[t]      = scale;
        s[32 + t] = beta[t] - mean * scale;
    }
    __syncthreads();
    int i = blockIdx.x * 256 + t;
#pragma unroll
    for (int rep = 0; rep < 2; ++rep) {
        int i2 = i * 2 + rep;               // 1,280,000 vec4 total
        f32x4 v = o[i2];
        int c0 = (i2 & 7) * 4;
        f32x4 r;
#pragma unroll
        for (int j = 0; j < 4; ++j) {
            float y = v[j] * s[c0 + j] + s[32 + c0 + j];
            r[j] = (y >= 0.f) ? y : SLOPE * y;
        }
        o[i2] = r;
    }
}

// ---------------------------------------------------------------------------
extern "C" void kernel_launch(void* const* d_in, const int* in_sizes, int n_in,
                              void* d_out, int out_size, void* d_ws, size_t ws_size,
                              hipStream_t stream) {
    const float* feat  = (const float*)d_in[0];  // [N][32] f32
    const int*   nbr   = (const int*)d_in[1];    // [N][27] int32
    const float* w     = (const float*)d_in[2];  // [27][32][32] f32
    // d_in[3] = bias: cancels exactly in BN — unused
    const float* gamma = (const float*)d_in[4];
    const float* beta  = (const float*)d_in[5];

    char* ws = (char*)d_ws;                       // ws ~256 MB
    u16*   featb = (u16*)ws;                      // 10,240,000 B bf16 feat
    u16*   wp    = (u16*)(ws + 10240000);         // 55,296 B
    float* stats = (float*)(ws + 10240000 + 55296 + 64);
    stats = (float*)(((uintptr_t)stats + 63) & ~(uintptr_t)63);  // 4 KB lines

    prep<<<2500, 256, 0, stream>>>(w, feat, wp, featb);
    conv_mfma<<<CBLK, 256, 0, stream>>>(featb, nbr, (const i32x4*)wp,
                                        (float*)d_out, stats);
    apply_bn<<<2500, 256, 0, stream>>>((f32x4*)d_out, stats, gamma, beta);
}